// Round 5
// baseline (184.706 us; speedup 1.0000x reference)
//
#include <hip/hip_runtime.h>
#include <hip/hip_bf16.h>

#define T_SEQ 2048
#define D_DIM 1024
#define NB 4

typedef __attribute__((ext_vector_type(8))) short short8;
typedef __attribute__((ext_vector_type(4))) float f32x4;

__device__ __forceinline__ unsigned short f2bf(float f) {
    unsigned int u = __float_as_uint(f);
    u = (u + 0x7FFFu + ((u >> 16) & 1u)) >> 16;
    return (unsigned short)u;
}

__global__ void cast_kernel(const float4* __restrict__ in, ushort4* __restrict__ out, int n4) {
    int i = blockIdx.x * 256 + threadIdx.x;
    if (i < n4) {
        float4 f = in[i];
        ushort4 o;
        o.x = f2bf(f.x); o.y = f2bf(f.y); o.z = f2bf(f.z); o.w = f2bf(f.w);
        out[i] = o;
    }
}

#define GLD(gp, lp) __builtin_amdgcn_global_load_lds( \
    (__attribute__((address_space(1))) void*)(gp), \
    (__attribute__((address_space(3))) void*)(lp), 16, 0, 0)

// ---------------------------------------------------------------------------
// 256x256 tile, BK=64, 8 waves (2x4), wave-tile 128x64 (8x4 frags) — m201
// geometry: per K-tile/wave 24 ds_read_b128 (~288cy) vs 64 MFMA (~310cy), so
// the matrix pipe, not the LDS pipe, is the limiter (the 128² core's 64x64
// wave-tile was LDS-read-bound: 96cy reads vs 78cy MFMA).
// Sync: proven r4 skeleton — BAR1 (stage target free) / STAGE(t+1) /
// vmcnt(8) counted (tile t landed, t+1 in flight) / BAR2 / compute; compute
// split in 2 k-half phases {12 ds_read, lgkmcnt(0), 32 MFMA} with setprio.
// T2 swizzle: row stride = 128B = full bank window; slot = chunk ^ (row&7)
// on 16B chunks, same involution on the global source (stage) and ds_read.
// ---------------------------------------------------------------------------
__global__ __launch_bounds__(512, 2) void qkv_gemm256(const unsigned short* __restrict__ xb,
                                                      const unsigned short* __restrict__ wb,
                                                      unsigned short* __restrict__ Qb,
                                                      unsigned short* __restrict__ Kb,
                                                      unsigned short* __restrict__ Vt) {
    __shared__ __align__(16) unsigned short As[2][256 * 64];
    __shared__ __align__(16) unsigned short Bs[2][256 * 64];
    const int tid  = threadIdx.x;
    const int lane = tid & 63;
    const int wave = tid >> 6;
    const int wm   = wave >> 2;          // 0..1 : rows wm*128
    const int wn   = wave & 3;           // 0..3 : cols wn*64
    const int lo   = lane & 15;
    const int hi   = lane >> 4;

    // wg < 256: QK gemm (A=xb M=8192, B=wb[0:2048] N-rows); else V^T via
    // operand swap (A=Wv rows=e, B=xb rows=t) so stores stay contiguous.
    const int wg = blockIdx.x;
    const unsigned short *Ap, *Bp;
    int bmA, bnB;
    if (wg < 256) { bmA = wg >> 3; bnB = wg & 7;               Ap = xb;               Bp = wb; }
    else          { int v = wg - 256; bmA = v >> 5; bnB = v & 31; Ap = wb + 2 * 1048576; Bp = xb; }

    // staging: 4 A-chunks + 4 B-chunks per thread per K-tile (16B each).
    // chunk index c = j*512+tid -> row = c>>3, slot = c&7; source chunk is
    // inverse-swizzled so LDS slot s of row r holds global chunk s^(r&7).
    const unsigned short* Asrc[4];
    const unsigned short* Bsrc[4];
    int ldst[4];
#pragma unroll
    for (int j = 0; j < 4; ++j) {
        const int c = j * 512 + tid, r = c >> 3, s = c & 7;
        Asrc[j] = Ap + (size_t)(bmA * 256 + r) * 1024 + ((s ^ (r & 7)) << 3);
        Bsrc[j] = Bp + (size_t)(bnB * 256 + r) * 1024 + ((s ^ (r & 7)) << 3);
        ldst[j] = c * 8;
    }

#define STG256(t, buf) do { const int kk_ = (t) << 6; \
        GLD(Asrc[0] + kk_, As[buf] + ldst[0]); \
        GLD(Asrc[1] + kk_, As[buf] + ldst[1]); \
        GLD(Asrc[2] + kk_, As[buf] + ldst[2]); \
        GLD(Asrc[3] + kk_, As[buf] + ldst[3]); \
        GLD(Bsrc[0] + kk_, Bs[buf] + ldst[0]); \
        GLD(Bsrc[1] + kk_, Bs[buf] + ldst[1]); \
        GLD(Bsrc[2] + kk_, Bs[buf] + ldst[2]); \
        GLD(Bsrc[3] + kk_, Bs[buf] + ldst[3]); } while (0)

    f32x4 acc[8][4] = {};

    STG256(0, 0);
    for (int t = 0; t < 16; ++t) {       // K = 1024 = 16 tiles of 64
        const int cur = t & 1;
        __builtin_amdgcn_s_barrier();    // BAR1: all reads of buf^1 retired (lgkmcnt-drained)
        if (t < 15) {
            STG256(t + 1, cur ^ 1);
            asm volatile("s_waitcnt vmcnt(8)" ::: "memory");   // own tile-t loads done; t+1 in flight
        } else {
            asm volatile("s_waitcnt vmcnt(0)" ::: "memory");
        }
        __builtin_amdgcn_s_barrier();    // BAR2: tile t fully landed for all waves
        __builtin_amdgcn_sched_barrier(0);

#pragma unroll
        for (int kh = 0; kh < 2; ++kh) {
            short8 av[8], bv[4];
#pragma unroll
            for (int mf = 0; mf < 8; ++mf) {
                const int row = wm * 128 + mf * 16 + lo;
                av[mf] = *(const short8*)&As[cur][row * 64 + (((kh * 4 + hi) ^ (row & 7)) << 3)];
            }
#pragma unroll
            for (int nf = 0; nf < 4; ++nf) {
                const int row = wn * 64 + nf * 16 + lo;
                bv[nf] = *(const short8*)&Bs[cur][row * 64 + (((kh * 4 + hi) ^ (row & 7)) << 3)];
            }
            asm volatile("s_waitcnt lgkmcnt(0)" ::: "memory");
            __builtin_amdgcn_sched_barrier(0);   // MFMA must not hoist above the drain (rule #18)

            __builtin_amdgcn_s_setprio(1);
#pragma unroll
            for (int mf = 0; mf < 8; ++mf)
#pragma unroll
                for (int nf = 0; nf < 4; ++nf)
                    acc[mf][nf] = __builtin_amdgcn_mfma_f32_16x16x32_bf16(av[mf], bv[nf], acc[mf][nf], 0, 0, 0);
            __builtin_amdgcn_s_setprio(0);
        }
    }
#undef STG256

    if (wg < 256) {
        unsigned short* O = (bnB < 4) ? Qb : Kb;
        const int rb = bmA * 256 + wm * 128 + hi * 4;
        const int cb = ((bnB & 3) * 256) + wn * 64 + lo;
#pragma unroll
        for (int mf = 0; mf < 8; ++mf)
#pragma unroll
            for (int nf = 0; nf < 4; ++nf)
#pragma unroll
                for (int r = 0; r < 4; ++r)
                    O[(size_t)(rb + mf * 16 + r) * D_DIM + (cb + nf * 16)] = f2bf(acc[mf][nf][r]);
    } else {
        const int eb = bmA * 256 + wm * 128 + hi * 4;
        const int tb = bnB * 256 + wn * 64 + lo;
#pragma unroll
        for (int mf = 0; mf < 8; ++mf)
#pragma unroll
            for (int nf = 0; nf < 4; ++nf)
#pragma unroll
                for (int r = 0; r < 4; ++r) {
                    const int e  = eb + mf * 16 + r;
                    const int tg = tb + nf * 16;
                    Vt[((size_t)(tg >> 11) * D_DIM + e) * T_SEQ + (tg & 2047)] = f2bf(acc[mf][nf][r]);
                }
    }
}

// ---------------------------------------------------------------------------
// 128x128 core (r4, unchanged): depth-2 prefetch over 3 buffers, counted
// vmcnt, T2 swizzle at 4-chunk rows. Used by s_gemm / pv_gemm.
// ---------------------------------------------------------------------------
__device__ __forceinline__ void gemm_core(const unsigned short* __restrict__ A,
                                          const unsigned short* __restrict__ B,
                                          int lda, int ldb, int bm, int bn, int kend,
                                          f32x4 acc[4][4]) {
    __shared__ __align__(16) unsigned short As[3][128 * 32];
    __shared__ __align__(16) unsigned short Bs[3][128 * 32];
    const int tid  = threadIdx.x;
    const int lane = tid & 63;
    const int wave = tid >> 6;
    const int wm   = (wave >> 1) * 64;
    const int wn   = (wave & 1) * 64;
    const int lo   = lane & 15;
    const int hi   = lane >> 4;
    const int r0   = tid >> 2;
    const int q0   = (((tid & 3) ^ ((r0 >> 1) & 3)) * 8);

    const unsigned short* Arow0 = A + (size_t)(bm * 128 + r0) * lda + q0;
    const unsigned short* Arow1 = A + (size_t)(bm * 128 + r0 + 64) * lda + q0;
    const unsigned short* Brow0 = B + (size_t)(bn * 128 + r0) * ldb + q0;
    const unsigned short* Brow1 = B + (size_t)(bn * 128 + r0 + 64) * ldb + q0;

#define STAGE(t, buf) do { const int kk_ = (t) << 5; \
        GLD(Arow0 + kk_, As[buf] + tid * 8); \
        GLD(Arow1 + kk_, As[buf] + (tid + 256) * 8); \
        GLD(Brow0 + kk_, Bs[buf] + tid * 8); \
        GLD(Brow1 + kk_, Bs[buf] + (tid + 256) * 8); } while (0)

    const int nt = kend >> 5;
    STAGE(0, 0);
    STAGE(1, 1);

    int aoff[4], boff[4];
#pragma unroll
    for (int m = 0; m < 4; ++m) {
        const int ra = wm + m * 16 + lo;
        const int rb = wn + m * 16 + lo;
        aoff[m] = ra * 32 + ((hi ^ ((ra >> 1) & 3)) * 8);
        boff[m] = rb * 32 + ((hi ^ ((rb >> 1) & 3)) * 8);
    }

    int cur = 0;
    for (int t = 0; t < nt; ++t) {
        __builtin_amdgcn_s_barrier();
        if (t + 2 < nt) {
            int nb = cur + 2; if (nb >= 3) nb -= 3;
            STAGE(t + 2, nb);
            asm volatile("s_waitcnt vmcnt(8)" ::: "memory");
        } else if (t + 1 < nt) {
            asm volatile("s_waitcnt vmcnt(4)" ::: "memory");
        } else {
            asm volatile("s_waitcnt vmcnt(0)" ::: "memory");
        }
        __builtin_amdgcn_s_barrier();
        __builtin_amdgcn_sched_barrier(0);

        short8 av[4], bv[4];
#pragma unroll
        for (int m = 0; m < 4; ++m) av[m] = *(const short8*)&As[cur][aoff[m]];
#pragma unroll
        for (int n = 0; n < 4; ++n) bv[n] = *(const short8*)&Bs[cur][boff[n]];
        asm volatile("s_waitcnt lgkmcnt(0)" ::: "memory");
        __builtin_amdgcn_sched_barrier(0);

        __builtin_amdgcn_s_setprio(1);
#pragma unroll
        for (int m = 0; m < 4; ++m)
#pragma unroll
            for (int n = 0; n < 4; ++n)
                acc[m][n] = __builtin_amdgcn_mfma_f32_16x16x32_bf16(av[m], bv[n], acc[m][n], 0, 0, 0);
        __builtin_amdgcn_s_setprio(0);

        cur += 1; if (cur >= 3) cur = 0;
    }
#undef STAGE
}

// Flat grid of exactly 544 working tiles (136 causal tiles x 4 batches).
__global__ __launch_bounds__(256) void s_gemm(const unsigned short* __restrict__ Qb,
                                              const unsigned short* __restrict__ Kb,
                                              float* __restrict__ S) {
    const int d = blockIdx.x;
    const int j = d & 7;
    const int z = j >> 1;
    int i = (j & 1) * 68 + (d >> 3);
    int bm = 0;
    while (i >= bm + 1) { i -= (bm + 1); ++bm; }
    const int bn = i;

    const unsigned short* Ap = Qb + (size_t)z * T_SEQ * D_DIM;
    const unsigned short* Bp = Kb + (size_t)z * T_SEQ * D_DIM;
    f32x4 acc[4][4] = {};
    gemm_core(Ap, Bp, D_DIM, D_DIM, bm, bn, D_DIM, acc);

    float* Sp = S + (size_t)z * T_SEQ * T_SEQ;
    const float scale = 0.03125f;
    const int lane = threadIdx.x & 63, wave = threadIdx.x >> 6;
    const int rb = bm * 128 + (wave >> 1) * 64 + ((lane >> 4) << 2);
    const int cb = bn * 128 + (wave & 1) * 64 + (lane & 15);
#pragma unroll
    for (int m = 0; m < 4; ++m)
#pragma unroll
        for (int n = 0; n < 4; ++n)
#pragma unroll
            for (int r = 0; r < 4; ++r) {
                int row = rb + m * 16 + r;
                int col = cb + n * 16;
                if (col <= row) Sp[(size_t)row * T_SEQ + col] = acc[m][n][r] * scale;
            }
}

__global__ __launch_bounds__(256) void softmax_kernel(const float* __restrict__ S,
                                                      unsigned short* __restrict__ P) {
    const int row = blockIdx.x;
    const int b = row >> 11, i = row & 2047;
    const float* srow = S + ((size_t)b * T_SEQ + i) * T_SEQ;
    unsigned short* prow = P + ((size_t)b * T_SEQ + i) * T_SEQ;
    __shared__ float buf[T_SEQ];
    __shared__ float red[4];
    const int tid = threadIdx.x, lane = tid & 63, wave = tid >> 6;
    const int len = i + 1;
    const int padlen = ((i >> 7) + 1) * 128;

    float m = -1e30f;
    for (int j = tid; j < len; j += 256) { float s = srow[j]; buf[j] = s; m = fmaxf(m, s); }
#pragma unroll
    for (int off = 32; off; off >>= 1) m = fmaxf(m, __shfl_xor(m, off, 64));
    if (lane == 0) red[wave] = m;
    __syncthreads();
    m = fmaxf(fmaxf(red[0], red[1]), fmaxf(red[2], red[3]));
    __syncthreads();

    float s = 0.f;
    for (int j = tid; j < len; j += 256) { float e = __expf(buf[j] - m); buf[j] = e; s += e; }
#pragma unroll
    for (int off = 32; off; off >>= 1) s += __shfl_xor(s, off, 64);
    if (lane == 0) red[wave] = s;
    __syncthreads();
    s = red[0] + red[1] + red[2] + red[3];
    float inv = 1.f / s;

    for (int j = tid; j < padlen; j += 256)
        prow[j] = (j < len) ? f2bf(buf[j] * inv) : (unsigned short)0;
}

// Flat grid of 512 (16 bm x 8 bn x 4 batches); causal K-bound kend=(bm+1)*128.
__global__ __launch_bounds__(256) void pv_gemm(const unsigned short* __restrict__ P,
                                               const unsigned short* __restrict__ Vt,
                                               float* __restrict__ Out) {
    const int d = blockIdx.x;
    const int j = d & 7;
    const int z = j >> 1;
    const int t = (j & 1) * 64 + (d >> 3);
    const int bm = t >> 3, bn = t & 7;

    const unsigned short* Ap = P + (size_t)z * T_SEQ * T_SEQ;
    const unsigned short* Bp = Vt + (size_t)z * D_DIM * T_SEQ;
    f32x4 acc[4][4] = {};
    gemm_core(Ap, Bp, T_SEQ, T_SEQ, bm, bn, (bm + 1) * 128, acc);

    float* Op = Out + (size_t)z * T_SEQ * D_DIM;
    const int lane = threadIdx.x & 63, wave = threadIdx.x >> 6;
    const int rb = bm * 128 + (wave >> 1) * 64 + ((lane >> 4) << 2);
    const int cb = bn * 128 + (wave & 1) * 64 + (lane & 15);
#pragma unroll
    for (int m = 0; m < 4; ++m)
#pragma unroll
        for (int n = 0; n < 4; ++n)
#pragma unroll
            for (int r = 0; r < 4; ++r)
                Op[(size_t)(rb + m * 16 + r) * D_DIM + (cb + n * 16)] = acc[m][n][r];
}

extern "C" void kernel_launch(void* const* d_in, const int* in_sizes, int n_in,
                              void* d_out, int out_size, void* d_ws, size_t ws_size,
                              hipStream_t stream) {
    const float* x  = (const float*)d_in[0];
    const float* Wq = (const float*)d_in[1];
    const float* Wk = (const float*)d_in[2];
    const float* Wv = (const float*)d_in[3];
    float* out = (float*)d_out;
    char* ws = (char*)d_ws;

    unsigned short* xb = (unsigned short*)(ws);                 // 16 MB  x bf16 [8192,1024]
    unsigned short* wb = (unsigned short*)(ws + 16777216);      // 6 MB   Wq|Wk|Wv bf16
    unsigned short* Qb = (unsigned short*)(ws + 23068672);      // 16 MB
    unsigned short* Kb = (unsigned short*)(ws + 39845888);      // 16 MB
    unsigned short* Vt = (unsigned short*)(ws + 56623104);      // 16 MB  V^T per batch [1024][2048]
    float*          S  = (float*)(ws + 73400320);               // 64 MB  scores fp32
    unsigned short* P  = (unsigned short*)(ws + 140509184);     // 32 MB  probs bf16
    (void)ws_size; (void)in_sizes; (void)n_in; (void)out_size;

    cast_kernel<<<8192, 256, 0, stream>>>((const float4*)x,  (ushort4*)xb, 2097152);
    cast_kernel<<<1024, 256, 0, stream>>>((const float4*)Wq, (ushort4*)(wb),           262144);
    cast_kernel<<<1024, 256, 0, stream>>>((const float4*)Wk, (ushort4*)(wb + 1048576), 262144);
    cast_kernel<<<1024, 256, 0, stream>>>((const float4*)Wv, (ushort4*)(wb + 2097152), 262144);

    qkv_gemm256<<<384, 512, 0, stream>>>(xb, wb, Qb, Kb, Vt);
    s_gemm<<<544, 256, 0, stream>>>(Qb, Kb, S);
    softmax_kernel<<<8192, 256, 0, stream>>>(S, P);
    pv_gemm<<<512, 256, 0, stream>>>(P, Vt, out);
}